// Round 8
// baseline (15463.374 us; speedup 1.0000x reference)
//
#include <hip/hip_runtime.h>
#include <math.h>

// Seq2SeqRNN fp32.
// Encoder: sync-free persistent recurrence (r6, unchanged).
// Decoder r8: r7 structure + REGISTER PREFETCH RINGS on all serial global-load
// dot loops (embT ring-15, w1e ring-15, l2W ring-5, l3W ring-7, encout ring-8
// dual-stream). r7 counters showed 214 GB/s fetch + 8% VALU: every phase was a
// serial latency chain (~1 load in flight, 4 waves/CU). Rings give 5-15x MLP.
// Accumulation order unchanged -> bit-identical output vs r7.

typedef unsigned long long ull;
typedef float v2f __attribute__((ext_vector_type(2)));

#define DINL static __device__ __forceinline__

DINL float sigm(float x) { return 1.0f / (1.0f + expf(-x)); }
DINL float dot4f(float4 a, float4 b) { return a.x*b.x + a.y*b.y + a.z*b.z + a.w*b.w; }

DINL ull packmax(float x, int v) {
  unsigned u = __float_as_uint(x);
  u = (u & 0x80000000u) ? ~u : (u | 0x80000000u);
  return ((ull)u << 32) | (unsigned)(~v);  // ties -> smaller v wins
}
DINL ull umax64(ull a, ull b) { return a > b ? a : b; }

DINL float atl(const float* p) {
  unsigned u = __hip_atomic_load((const unsigned*)p, __ATOMIC_RELAXED,
                                 __HIP_MEMORY_SCOPE_AGENT);
  return __uint_as_float(u);
}
DINL void atsf(float* p, float v) {
  __hip_atomic_exchange((unsigned*)p, __float_as_uint(v), __ATOMIC_RELAXED,
                        __HIP_MEMORY_SCOPE_AGENT);
}
DINL ull atl64(const ull* p) {
  return __hip_atomic_load(p, __ATOMIC_RELAXED, __HIP_MEMORY_SCOPE_AGENT);
}
DINL void ats64(ull* p, ull v) {
  __hip_atomic_exchange(p, v, __ATOMIC_RELAXED, __HIP_MEMORY_SCOPE_AGENT);
}

// counting grid barrier: one fetch_add + tid0-only poll. grid = 256 WGs exactly.
DINL void gbar(unsigned* cnt, unsigned target, int tid) {
  asm volatile("s_waitcnt vmcnt(0)" ::: "memory");
  __syncthreads();
  if (tid == 0) {
    __hip_atomic_fetch_add(cnt, 1u, __ATOMIC_RELAXED, __HIP_MEMORY_SCOPE_AGENT);
    while (__hip_atomic_load(cnt, __ATOMIC_RELAXED, __HIP_MEMORY_SCOPE_AGENT) < target)
      __builtin_amdgcn_s_sleep(4);
  }
  __syncthreads();
}

// ---------------- embedding gather (300 = 75 float4)
__global__ __launch_bounds__(256) void k_embed(const float4* __restrict__ E,
                                               const int* __restrict__ inp,
                                               float4* __restrict__ out) {
  int i = blockIdx.x * 256 + threadIdx.x;
  if (i >= 8192 * 75) return;
  int row = i / 75, q = i - row * 75;
  out[i] = E[(size_t)inp[row] * 75 + q];
}

// ---------------- transpose B[c*R+r] = A[r*C+c]
__global__ __launch_bounds__(256) void k_transpose(const float* __restrict__ A,
                                                   float* __restrict__ B, int R, int C) {
  __shared__ float tile[32][33];
  int c0 = blockIdx.x * 32, r0 = blockIdx.y * 32;
  int tx = threadIdx.x & 31, ty = threadIdx.x >> 5;
  for (int i = 0; i < 32; i += 8) {
    int r = r0 + ty + i, c = c0 + tx;
    if (r < R && c < C) tile[ty + i][tx] = A[(size_t)r * C + c];
  }
  __syncthreads();
  for (int i = 0; i < 32; i += 8) {
    int c = c0 + ty + i, r = r0 + tx;
    if (c < C && r < R) B[(size_t)c * R + r] = tile[tx][ty + i];
  }
}

// ---------------- pack Whh[2][768][256] -> W2[2][128 kp][768 gc][2]
__global__ __launch_bounds__(256) void k_packW(const float* __restrict__ Whh,
                                               float* __restrict__ W2) {
  int i = blockIdx.x * 256 + threadIdx.x;
  if (i >= 196608) return;
  int d = i / 98304, r = i - d * 98304, kp = r / 768, gc = r - kp * 768;
  const float* src = Whh + (size_t)d * 196608 + (size_t)gc * 256 + kp * 2;
  float* dst = W2 + (size_t)i * 2;
  dst[0] = src[0];
  dst[1] = src[1];
}

// ---------------- fp32 GEMM-NT: C[n,m] = sum_k A[n,k]*B[m,k] + bias[m]
__global__ __launch_bounds__(256) void k_gemm128(const float* __restrict__ A,
                                                 const float* __restrict__ B,
                                                 const float* __restrict__ bias,
                                                 float* __restrict__ C,
                                                 int N, int M, int K) {
  __shared__ float As[8][132];
  __shared__ float Bs[8][132];
  const int tid = threadIdx.x;
  const int bn = blockIdx.x * 128, bm = blockIdx.y * 128;
  const int tn = (tid >> 4) << 3, tm = (tid & 15) << 3;
  const int r = tid & 127;
  const bool isB = tid >= 128;
  const float* src = isB ? (B + (size_t)(bm + r) * K) : (A + (size_t)(bn + r) * K);
  const bool rowok = isB ? (bm + r < M) : (bn + r < N);
  float acc[8][8] = {};
  for (int k0 = 0; k0 < K; k0 += 8) {
    float v[8];
    if (rowok && k0 + 8 <= K) {
      float4 p0 = *(const float4*)(src + k0);
      float4 p1 = *(const float4*)(src + k0 + 4);
      v[0]=p0.x; v[1]=p0.y; v[2]=p0.z; v[3]=p0.w;
      v[4]=p1.x; v[5]=p1.y; v[6]=p1.z; v[7]=p1.w;
    } else {
#pragma unroll
      for (int j = 0; j < 8; ++j) v[j] = (rowok && k0 + j < K) ? src[k0 + j] : 0.0f;
    }
    float (*dst)[132] = isB ? Bs : As;
#pragma unroll
    for (int j = 0; j < 8; ++j) dst[j][r] = v[j];
    __syncthreads();
#pragma unroll
    for (int kk = 0; kk < 8; ++kk) {
      float a[8], b[8];
      *(float4*)&a[0] = *(const float4*)&As[kk][tn];
      *(float4*)&a[4] = *(const float4*)&As[kk][tn + 4];
      *(float4*)&b[0] = *(const float4*)&Bs[kk][tm];
      *(float4*)&b[4] = *(const float4*)&Bs[kk][tm + 4];
#pragma unroll
      for (int i = 0; i < 8; ++i)
#pragma unroll
        for (int j = 0; j < 8; ++j) acc[i][j] += a[i] * b[j];
    }
    __syncthreads();
  }
#pragma unroll
  for (int i = 0; i < 8; ++i) {
    int row = bn + tn + i;
    if (row >= N) continue;
#pragma unroll
    for (int j = 0; j < 8; ++j) {
      int col = bm + tm + j;
      if (col < M) C[(size_t)row * M + col] = acc[i][j] + (bias ? bias[col] : 0.0f);
    }
  }
}

// ---------------- sync-free encoder recurrence (r6, unchanged)
__global__ __launch_bounds__(256) void k_enc_rec(
    const float* __restrict__ giF, const float* __restrict__ giB,
    const float* __restrict__ W2, const float* __restrict__ bhh,
    float* __restrict__ y) {
  const int b0 = blockIdx.x * 2;
  const int dir = blockIdx.y;
  const int c = threadIdx.x;
  const float* gi = dir ? giB : giF;
  const v2f* Wv = (const v2f*)(W2 + (size_t)dir * 196608);
  const float* bh = bhh + dir * 768;

  __shared__ __align__(16) float hls[2][2][258];
  for (int i = c; i < 2 * 2 * 258; i += 256) ((float*)hls)[i] = 0.0f;
  __syncthreads();

  const float bhr = bh[c], bhz = bh[256 + c], bhn = bh[512 + c];
  const int tt0 = dir ? 127 : 0;
  const float* g0p = gi + (size_t)tt0 * 49152 + (size_t)b0 * 768;
  float g0r = g0p[c], g0z = g0p[256 + c], g0n = g0p[512 + c];
  float g1r = g0p[768 + c], g1z = g0p[1024 + c], g1n = g0p[1280 + c];

  for (int t = 0; t < 128; ++t) {
    const int cu = t & 1;
    float p0r = 0, p0z = 0, p0n = 0, p1r = 0, p1z = 0, p1n = 0;
    if (t < 127) {
      const int tn_ = dir ? 126 - t : t + 1;
      const float* gp = gi + (size_t)tn_ * 49152 + (size_t)b0 * 768;
      p0r = gp[c]; p0z = gp[256 + c]; p0n = gp[512 + c];
      p1r = gp[768 + c]; p1z = gp[1024 + c]; p1n = gp[1280 + c];
    }
    v2f a0r = {0,0}, a0z = {0,0}, a0n = {0,0};
    v2f a1r = {0,0}, a1z = {0,0}, a1n = {0,0};
    const float* h0p = &hls[cu][0][0];
    const float* h1p = &hls[cu][1][0];
#pragma unroll 4
    for (int kp = 0; kp < 128; ++kp) {
      v2f wr = Wv[kp * 768 + c];
      v2f wz = Wv[kp * 768 + 256 + c];
      v2f wn = Wv[kp * 768 + 512 + c];
      v2f h0 = *(const v2f*)&h0p[kp * 2];
      v2f h1 = *(const v2f*)&h1p[kp * 2];
      a0r += h0 * wr; a0z += h0 * wz; a0n += h0 * wn;
      a1r += h1 * wr; a1z += h1 * wz; a1n += h1 * wn;
    }
    float r0 = sigm(g0r + a0r.x + a0r.y + bhr);
    float z0 = sigm(g0z + a0z.x + a0z.y + bhz);
    float n0 = tanhf(g0n + r0 * (a0n.x + a0n.y + bhn));
    float h0new = (1.f - z0) * n0 + z0 * h0p[c];
    float r1 = sigm(g1r + a1r.x + a1r.y + bhr);
    float z1 = sigm(g1z + a1z.x + a1z.y + bhz);
    float n1 = tanhf(g1n + r1 * (a1n.x + a1n.y + bhn));
    float h1new = (1.f - z1) * n1 + z1 * h1p[c];
    hls[cu ^ 1][0][c] = h0new;
    hls[cu ^ 1][1][c] = h1new;
    const int tw = dir ? 127 - t : t;
    float* yp = y + (size_t)tw * 32768 + (size_t)b0 * 512 + dir * 256 + c;
    yp[0] = h0new;
    yp[512] = h1new;
    g0r = p0r; g0z = p0z; g0n = p0n; g1r = p1r; g1z = p1z; g1n = p1n;
    __syncthreads();
  }
}

// ---------------- hcat[2][64][512]
__global__ __launch_bounds__(256) void k_hcat(const float* __restrict__ x1,
                                              const float* __restrict__ encout,
                                              float* __restrict__ hcat) {
  int i = blockIdx.x * 256 + threadIdx.x;
  int l = i >> 15, r = i & 32767, b = r >> 9, d = r & 511;
  const float* src = l ? encout : x1;
  int ts = (d < 256) ? 127 : 0;
  hcat[i] = src[((size_t)(ts << 6) + b) * 512 + d];
}

// ---------------- GRU cell phase with LDS-resident weights.
DINL void gru_lds(int cch, int bch, int tid,
                  const float* __restrict__ xin, const float* __restrict__ hin,
                  float* __restrict__ hout, float* __restrict__ houtT,
                  const float* Wg, const float* biass, float* scr) {
  float* xs = scr;           // [16][300]
  float* hs = scr + 4800;    // [16][300]
  const int b0 = bch * 16;
  for (int i = tid; i < 4800; i += 256) {
    int row = i / 300, q = i - row * 300;
    xs[i] = atl(xin + (size_t)(b0 + row) * 300 + q);
    hs[i] = atl(hin + (size_t)(b0 + row) * 300 + q);
  }
  __syncthreads();
  const int cl = tid & 15, bl = tid >> 4;
  const int c = cch * 16 + cl, bq = b0 + bl;
  if (c < 300) {
    float gir = biass[cl],      giz = biass[16 + cl], gin = biass[32 + cl];
    float ghr = biass[48 + cl], ghz = biass[64 + cl], ghn = biass[80 + cl];
    const float4* xr = (const float4*)(xs + bl * 300);
    const float4* hr = (const float4*)(hs + bl * 300);
    const float4* w0 = (const float4*)(Wg + (0 * 16 + cl) * 308);
    const float4* w1 = (const float4*)(Wg + (1 * 16 + cl) * 308);
    const float4* w2 = (const float4*)(Wg + (2 * 16 + cl) * 308);
    const float4* w3 = (const float4*)(Wg + (3 * 16 + cl) * 308);
    const float4* w4 = (const float4*)(Wg + (4 * 16 + cl) * 308);
    const float4* w5 = (const float4*)(Wg + (5 * 16 + cl) * 308);
    for (int q = 0; q < 75; ++q) {
      float4 xv = xr[q], hv = hr[q];
      gir += dot4f(xv, w0[q]);
      giz += dot4f(xv, w1[q]);
      gin += dot4f(xv, w2[q]);
      ghr += dot4f(hv, w3[q]);
      ghz += dot4f(hv, w4[q]);
      ghn += dot4f(hv, w5[q]);
    }
    float r = sigm(gir + ghr), z = sigm(giz + ghz);
    float n = tanhf(gin + r * ghn);
    float hnew = (1.f - z) * n + z * hs[bl * 300 + c];
    atsf(&hout[(size_t)bq * 300 + c], hnew);
    if (houtT) atsf(&houtT[(size_t)c * 64 + bq], hnew);
  }
  __syncthreads();
}

// ---------------- persistent decoder: all 32 steps, 256 WGs (1/CU).
__global__ __launch_bounds__(256) void k_dec_all(
    float* __restrict__ dech, float* __restrict__ h1T, float* __restrict__ xdec,
    ull* __restrict__ bests, unsigned* __restrict__ cnt,
    const float* __restrict__ w1e, const float* __restrict__ encout,
    const float* __restrict__ l2W, const float* __restrict__ l2b,
    const float* __restrict__ l3W, const float* __restrict__ l3b,
    const float* __restrict__ Vatt, const float* __restrict__ embdec,
    const float* __restrict__ dWih, const float* __restrict__ dWhh,
    const float* __restrict__ dbih, const float* __restrict__ dbhh,
    const float* __restrict__ embT, const float* __restrict__ outb,
    float* __restrict__ out) {
  const int wg = blockIdx.x, tid = threadIdx.x;
  __shared__ __align__(16) float Wg[6 * 16 * 308];
  __shared__ __align__(16) float scr[9600];
  __shared__ float biass[96];

  int grole = -1, gcell = 0;
  if (wg < 76) { grole = wg; gcell = 0; }
  else if (wg < 152) { grole = wg - 76; gcell = 1; }
  const int cch = (grole >= 0) ? grole % 19 : 0;
  const int bch = (grole >= 0) ? grole / 19 : 0;
  if (grole >= 0) {
    const float* Wih = dWih + gcell * 270000;
    const float* Whh = dWhh + gcell * 270000;
    for (int i = tid; i < 96 * 300; i += 256) {
      int r = i / 300, k = i - r * 300;
      int g = r >> 4, cl = r & 15;
      int c = cch * 16 + cl;
      float v = 0.f;
      if (c < 300)
        v = (g < 3) ? Wih[(size_t)(g * 300 + c) * 300 + k]
                    : Whh[(size_t)((g - 3) * 300 + c) * 300 + k];
      Wg[(g * 16 + cl) * 308 + k] = v;
    }
    if (tid < 96) {
      int g = tid >> 4, cl = tid & 15;
      int c = cch * 16 + cl;
      float v = 0.f;
      if (c < 300)
        v = (g < 3) ? dbih[gcell * 900 + g * 300 + c]
                    : dbhh[gcell * 900 + (g - 3) * 300 + c];
      biass[tid] = v;
    }
  }
  __syncthreads();

  unsigned tgt = 0;
  for (int t = 0; t < 32; ++t) {
    const int cur = t & 1;
    float* hc = dech + cur * 38400;
    float* hn = dech + (cur ^ 1) * 38400;

    // ---- phase 1: attention + x build (wg < 64)
    if (wg < 64) {
      const int b = wg;
      float* h1s = scr;
      float* w2h = scr + 304;
      float* eXa = scr + 608;
      float* aa  = scr + 1424;
      float* red = scr + 1552;
      ull* redb  = (ull*)(scr + 1680);

      if (tid < 128) {
        ull m = 0ULL;
        if (t > 0) {
          m = atl64(&bests[(size_t)tid * 64 + b]);
          if (tid + 128 < 250) m = umax64(m, atl64(&bests[(size_t)(tid + 128) * 64 + b]));
        }
        redb[tid] = m;
      }
      for (int i = tid; i < 300; i += 256) h1s[i] = atl(hc + 19200 + b * 300 + i);
      __syncthreads();
      for (int s = 64; s > 0; s >>= 1) {
        if (tid < s) redb[tid] = umax64(redb[tid], redb[tid + s]);
        __syncthreads();
      }
      const int ib = (t > 0) ? (int)(~(unsigned)(redb[0] & 0xFFFFFFFFULL)) : 0;

      // w2h = l2W @ h1 + l2b  (ring-5)
      for (int m = tid; m < 300; m += 256) {
        const float4* wr = (const float4*)(l2W + (size_t)m * 300);
        const float4* hr = (const float4*)h1s;
        float acc = l2b[m];
        float4 pf[5];
#pragma unroll
        for (int j = 0; j < 5; ++j) pf[j] = wr[j];
        for (int q0 = 0; q0 < 75; q0 += 5) {
#pragma unroll
          for (int j = 0; j < 5; ++j) {
            float4 w = pf[j];
            int qn = q0 + 5 + j; qn = (qn < 75) ? qn : 0;
            pf[j] = wr[qn];
            acc += dot4f(w, hr[q0 + j]);
          }
        }
        w2h[m] = acc;
      }
      __syncthreads();

      // scores (ring-15 on w1e)
      if (tid < 128) {
        const float4* wp = (const float4*)(w1e + ((size_t)(tid << 6) + b) * 300);
        const float4* vp = (const float4*)Vatt;
        const float4* hp = (const float4*)w2h;
        float acc = 0.f;
        float4 pf[15];
#pragma unroll
        for (int j = 0; j < 15; ++j) pf[j] = wp[j];
        for (int q0 = 0; q0 < 75; q0 += 15) {
#pragma unroll
          for (int j = 0; j < 15; ++j) {
            float4 w = pf[j];
            int qn = q0 + 15 + j; qn = (qn < 75) ? qn : 0;
            pf[j] = wp[qn];
            const int q = q0 + j;
            float4 h = hp[q], v = vp[q];
            acc += tanhf(w.x + h.x) * v.x + tanhf(w.y + h.y) * v.y +
                   tanhf(w.z + h.z) * v.z + tanhf(w.w + h.w) * v.w;
          }
        }
        aa[tid] = acc;
        red[tid] = acc;
      }
      __syncthreads();
      for (int s = 64; s > 0; s >>= 1) {
        if (tid < s) red[tid] = fmaxf(red[tid], red[tid + s]);
        __syncthreads();
      }
      float mx = red[0];
      __syncthreads();
      if (tid < 128) {
        float ex = expf(aa[tid] - mx);
        aa[tid] = ex;
        red[tid] = ex;
      }
      __syncthreads();
      for (int s = 64; s > 0; s >>= 1) {
        if (tid < s) red[tid] += red[tid + s];
        __syncthreads();
      }
      float inv = 1.0f / red[0];
      __syncthreads();
      if (tid < 128) aa[tid] *= inv;
      for (int d = tid; d < 300; d += 256) eXa[d] = embdec[(size_t)ib * 300 + d];
      __syncthreads();

      // Xa (dual-stream ring-8 over encout, all 256 threads: d0=tid, d1=tid+256)
      {
        const int d0 = tid, d1 = tid + 256;
        const float* ebase = encout + (size_t)b * 512;
        float pA[8], pB[8];
#pragma unroll
        for (int j = 0; j < 8; ++j) {
          pA[j] = ebase[(size_t)j * 32768 + d0];
          pB[j] = ebase[(size_t)j * 32768 + d1];
        }
        float acc0 = 0.f, acc1 = 0.f;
        for (int s0 = 0; s0 < 128; s0 += 8) {
#pragma unroll
          for (int j = 0; j < 8; ++j) {
            float a = aa[s0 + j];
            acc0 += a * pA[j];
            acc1 += a * pB[j];
            int sn = s0 + 8 + j; sn = (sn < 128) ? sn : 0;
            pA[j] = ebase[(size_t)sn * 32768 + d0];
            pB[j] = ebase[(size_t)sn * 32768 + d1];
          }
        }
        eXa[300 + d0] = acc0;
        eXa[300 + d1] = acc1;
      }
      __syncthreads();

      // xdec = l3W @ [e,Xa] + l3b  (ring-7, 203 = 7*29)
      for (int m = tid; m < 300; m += 256) {
        const float4* wr = (const float4*)(l3W + (size_t)m * 812);
        const float4* xr = (const float4*)eXa;
        float acc = l3b[m];
        float4 pf[7];
#pragma unroll
        for (int j = 0; j < 7; ++j) pf[j] = wr[j];
        for (int q0 = 0; q0 < 203; q0 += 7) {
#pragma unroll
          for (int j = 0; j < 7; ++j) {
            float4 w = pf[j];
            int qn = q0 + 7 + j; qn = (qn < 203) ? qn : 0;
            pf[j] = wr[qn];
            acc += dot4f(w, xr[q0 + j]);
          }
        }
        atsf(&xdec[b * 300 + m], acc);
      }
      __syncthreads();
    }
    gbar(cnt, 256u * (++tgt), tid);

    // ---- phase 2: GRU cell 0
    if (wg < 76)
      gru_lds(cch, bch, tid, xdec, hc, hn, nullptr, Wg, biass, scr);
    gbar(cnt, 256u * (++tgt), tid);

    // ---- phase 3: GRU cell 1 (+h1T)
    if (wg >= 76 && wg < 152)
      gru_lds(cch, bch, tid, hn, hc + 19200, hn + 19200, h1T, Wg, biass, scr);
    gbar(cnt, 256u * (++tgt), tid);

    // ---- phase 4: logits + argmax partials (ring-15 on embT)
    if (wg < 250) {
      const int v0 = wg * 128;
      const int vq = tid & 31, bo = tid >> 5;
      float acc[8][4];
#pragma unroll
      for (int i = 0; i < 8; ++i)
#pragma unroll
        for (int j = 0; j < 4; ++j) acc[i][j] = 0.f;
      float* hch = scr;  // [75][64]
      for (int kc = 0; kc < 4; ++kc) {
        __syncthreads();
        for (int i = tid; i < 4800; i += 256) hch[i] = atl(h1T + kc * 4800 + i);
        __syncthreads();
        const float* eb = embT + (size_t)kc * 75 * 32000 + v0 + (vq << 2);
        float4 pf[15];
#pragma unroll
        for (int j = 0; j < 15; ++j) pf[j] = *(const float4*)(eb + (size_t)j * 32000);
        for (int k0 = 0; k0 < 75; k0 += 15) {
#pragma unroll
          for (int j = 0; j < 15; ++j) {
            float4 ev = pf[j];
            int kn = k0 + 15 + j; kn = (kn < 75) ? kn : 0;
            pf[j] = *(const float4*)(eb + (size_t)kn * 32000);
            const int k = k0 + j;
            float hv[8];
            *(float4*)&hv[0] = *(const float4*)&hch[(k << 6) + (bo << 3)];
            *(float4*)&hv[4] = *(const float4*)&hch[(k << 6) + (bo << 3) + 4];
#pragma unroll
            for (int i = 0; i < 8; ++i) {
              acc[i][0] += hv[i] * ev.x;
              acc[i][1] += hv[i] * ev.y;
              acc[i][2] += hv[i] * ev.z;
              acc[i][3] += hv[i] * ev.w;
            }
          }
        }
      }
      float4 bo4 = *(const float4*)(outb + v0 + (vq << 2));
      float* outp = out + (size_t)t * 2048000;
      float* sacc = scr;  // [128 v][65] padded
      __syncthreads();
#pragma unroll
      for (int i = 0; i < 8; ++i) {
        const int b = (bo << 3) + i;
        float4 r;
        r.x = acc[i][0] + bo4.x; r.y = acc[i][1] + bo4.y;
        r.z = acc[i][2] + bo4.z; r.w = acc[i][3] + bo4.w;
        *(float4*)(outp + (size_t)b * 32000 + v0 + (vq << 2)) = r;
        sacc[((vq << 2) + 0) * 65 + b] = r.x;
        sacc[((vq << 2) + 1) * 65 + b] = r.y;
        sacc[((vq << 2) + 2) * 65 + b] = r.z;
        sacc[((vq << 2) + 3) * 65 + b] = r.w;
      }
      __syncthreads();
      if (tid < 64) {
        ull best = 0ULL;
#pragma unroll 4
        for (int v = 0; v < 128; ++v)
          best = umax64(best, packmax(sacc[v * 65 + tid], v0 + v));
        ats64(&bests[(size_t)wg * 64 + tid], best);
      }
      __syncthreads();
    }
    if (t < 31) gbar(cnt, 256u * (++tgt), tid);
  }
}

extern "C" void kernel_launch(void* const* d_in, const int* in_sizes, int n_in,
                              void* d_out_v, int out_size, void* d_ws, size_t ws_size,
                              hipStream_t stream) {
  (void)in_sizes; (void)n_in; (void)out_size; (void)ws_size;
  const float* emb_enc = (const float*)d_in[0];
  const float* eWih0   = (const float*)d_in[1];
  const float* eWhh0   = (const float*)d_in[2];
  const float* ebih0   = (const float*)d_in[3];
  const float* ebhh0   = (const float*)d_in[4];
  const float* eWih1   = (const float*)d_in[5];
  const float* eWhh1   = (const float*)d_in[6];
  const float* ebih1   = (const float*)d_in[7];
  const float* ebhh1   = (const float*)d_in[8];
  const float* Wout    = (const float*)d_in[9];
  const float* emb_dec = (const float*)d_in[10];
  const float* dWih    = (const float*)d_in[11];
  const float* dWhh    = (const float*)d_in[12];
  const float* dbih    = (const float*)d_in[13];
  const float* dbhh    = (const float*)d_in[14];
  const float* W1      = (const float*)d_in[15];
  const float* l2W     = (const float*)d_in[16];
  const float* l2b     = (const float*)d_in[17];
  const float* l3W     = (const float*)d_in[18];
  const float* l3b     = (const float*)d_in[19];
  const float* Vatt    = (const float*)d_in[20];
  const float* outb    = (const float*)d_in[21];
  const int* inp       = (const int*)d_in[22];
  float* d_out = (float*)d_out_v;

  float* ws = (float*)d_ws;
  size_t off = 0;
  auto take = [&](size_t n) { float* p = ws + off; off += (n + 3) & ~(size_t)3; return p; };
  float* embT   = take((size_t)300 * 32000);
  float* encout = take((size_t)8192 * 512);
  float* w1e    = take((size_t)8192 * 300);
  float* W1T    = take((size_t)300 * 512);
  float* hcat   = take((size_t)128 * 512);
  float* dech   = take((size_t)2 * 2 * 64 * 300);
  float* h1T    = take((size_t)300 * 64);
  float* xdec   = take((size_t)64 * 300);
  ull* bests    = (ull*)take((size_t)250 * 64 * 2);
  unsigned* cnt = (unsigned*)take((size_t)32);

  // encoder scratch in d_out (dead before decoder writes)
  float* emb  = d_out;
  float* gi0f = emb + 2457600;
  float* gi0b = gi0f + 6291456;
  float* x1   = gi0b + 6291456;
  float* gi1f = x1 + 4194304;
  float* gi1b = gi1f + 6291456;
  float* W2L0 = d_out + 33554432;
  float* W2L1 = W2L0 + 393216;

  hipMemsetAsync(cnt, 0, 32 * sizeof(unsigned), stream);

  k_embed<<<2400, 256, 0, stream>>>((const float4*)emb_enc, inp, (float4*)emb);
  k_transpose<<<dim3(10, 16), 256, 0, stream>>>(W1, W1T, 512, 300);
  k_transpose<<<dim3(10, 1000), 256, 0, stream>>>(emb_dec, embT, 32000, 300);
  k_packW<<<768, 256, 0, stream>>>(eWhh0, W2L0);
  k_packW<<<768, 256, 0, stream>>>(eWhh1, W2L1);

  // encoder layer 0
  k_gemm128<<<dim3(64, 6), 256, 0, stream>>>(emb, eWih0, ebih0, gi0f, 8192, 768, 300);
  k_gemm128<<<dim3(64, 6), 256, 0, stream>>>(emb, eWih0 + 230400, ebih0 + 768, gi0b, 8192, 768, 300);
  k_enc_rec<<<dim3(32, 2), 256, 0, stream>>>(gi0f, gi0b, W2L0, ebhh0, x1);

  // encoder layer 1
  k_gemm128<<<dim3(64, 6), 256, 0, stream>>>(x1, eWih1, ebih1, gi1f, 8192, 768, 512);
  k_gemm128<<<dim3(64, 6), 256, 0, stream>>>(x1, eWih1 + 393216, ebih1 + 768, gi1b, 8192, 768, 512);
  k_enc_rec<<<dim3(32, 2), 256, 0, stream>>>(gi1f, gi1b, W2L1, ebhh1, encout);

  // encoder epilogue
  k_hcat<<<256, 256, 0, stream>>>(x1, encout, hcat);
  k_gemm128<<<dim3(1, 3), 256, 0, stream>>>(hcat, Wout, nullptr, dech, 128, 300, 512);
  k_gemm128<<<dim3(64, 3), 256, 0, stream>>>(encout, W1T, nullptr, w1e, 8192, 300, 512);

  // persistent decoder
  k_dec_all<<<256, 256, 0, stream>>>(dech, h1T, xdec, bests, cnt,
                                     w1e, encout, l2W, l2b, l3W, l3b,
                                     Vatt, emb_dec, dWih, dWhh, dbih, dbhh,
                                     embT, outb, d_out);
}